// Round 9
// baseline (81.362 us; speedup 1.0000x reference)
//
#include <hip/hip_runtime.h>

#define HID   32
#define INCH  128
#define OUTD  8
#define BATCH 512
#define TLEN  512
#define TT    32
#define NCHUNK (TLEN / TT)

typedef __attribute__((ext_vector_type(2)))  float  f32x2;
typedef __attribute__((ext_vector_type(4)))  float  vf4;
typedef __attribute__((ext_vector_type(8)))  short  short8_t;
typedef __attribute__((ext_vector_type(16))) float  f32x16_t;
typedef __attribute__((ext_vector_type(2)))  int    i32x2;

// p_own + p[lane^32]  (HW-verified in rounds 6/8)
__device__ __forceinline__ float swap32_add(float p)
{
#if __has_builtin(__builtin_amdgcn_permlane32_swap)
    i32x2 r = __builtin_amdgcn_permlane32_swap(
        __float_as_int(p), __float_as_int(p), false, false);
    return __int_as_float(r[0]) + __int_as_float(r[1]);
#else
    return p + __shfl_xor(p, 32, 64);
#endif
}

// Split fp32 -> bf16 hi (bit-truncate) + bf16 lo (truncated residual).
__device__ __forceinline__ void split8(const float4 f0, const float4 f1,
                                       short8_t* hi, short8_t* lo)
{
    float x[8] = {f0.x, f0.y, f0.z, f0.w, f1.x, f1.y, f1.z, f1.w};
    short8_t h, l;
    #pragma unroll
    for (int e = 0; e < 8; ++e) {
        const unsigned u  = __float_as_uint(x[e]);
        const unsigned hb = u & 0xFFFF0000u;
        h[e] = (short)(u >> 16);
        const float r = x[e] - __uint_as_float(hb);
        l[e] = (short)(__float_as_uint(r) >> 16);
    }
    *hi = h; *lo = l;
}

// ---------------------------------------------------------------------------
// One block per batch row; 2 waves.
//   wave 0 (scan): h = relu(x_t + W_hh h), fp32. Per-step chain:
//     h (VGPR) -> 16 independent ds_bpermute_b32 (lane (ch,half) pulls
//     h[j], j = 16*half + k; VGPR->VGPR via LDS crossbar, NO ds_write and
//     no LDS memory on the chain) -> 4x4 fmac tree -> permlane32-swap
//     combine (verified) -> relu(+x). x_t preloaded per chunk into regs
//     from the transposed XOR-swizzled LDS tile (off-chain), as in round 6.
//   wave 1 (proj): split-bf16 MFMA 32x32x128 GEMM per chunk (verbatim from
//     the passing round-6 kernel); D stored transposed, 4x ds_write_b128.
// ---------------------------------------------------------------------------
__global__ __launch_bounds__(128, 1) void rnn_fused_kernel(
    const float* __restrict__ seq, const float* __restrict__ Wih,
    const float* __restrict__ Whh, const float* __restrict__ bih,
    const float* __restrict__ bhh, const float* __restrict__ Wfc,
    const float* __restrict__ bfc, float* __restrict__ out)
{
    __shared__ __align__(16) float xpb[2][TT * HID];   // transposed [ch][t], 8 KB
    __shared__ __align__(16) float hlds[HID];

    const int tid  = threadIdx.x;
    const int wid  = tid >> 6;
    const int l    = tid & 63;
    const int row  = blockIdx.x;

    if (wid == 0) {
        // ============================ SCAN ============================
        const int ch   = l & 31;
        const int half = l >> 5;
        const int jb4  = half * 64;                    // byte addr of h[16*half]
        const int m    = 4 * (ch & 7);                 // x swizzle (dwords)

        // W_hh[ch][16*half + k], k = 0..15
        float w[16];
        {
            const vf4* W4 = (const vf4*)(Whh + ch * HID + half * 16);
            #pragma unroll
            for (int q = 0; q < 4; ++q) {
                const vf4 t = W4[q];
                w[4 * q + 0] = t.x; w[4 * q + 1] = t.y;
                w[4 * q + 2] = t.z; w[4 * q + 3] = t.w;
            }
        }

        float h = 0.0f;                                // h[ch], lanes 0..31 live

        __builtin_amdgcn_s_setprio(1);
        for (int c = 0; c < NCHUNK; ++c) {
            __syncthreads();                           // chunk c published
            const float* xb = xpb[c & 1] + ch * TT;    // my channel's column
            vf4 xq[8];
            xq[0] = *(const vf4*)(xb + (0 ^ m));       // x[0..3]

            #pragma unroll
            for (int tt = 0; tt < TT; ++tt) {
                const float xv = xq[tt >> 2][tt & 3];
                const int hi = __float_as_int(h);
                // gather h[16*half + k] from lane (16*half + k) — all ops
                // independent; per-op every lane reads one source lane
                // (crossbar broadcast, conflict-free)
                float g[16];
                #pragma unroll
                for (int k = 0; k < 16; ++k)
                    g[k] = __int_as_float(
                        __builtin_amdgcn_ds_bpermute(jb4 + 4 * k, hi));
                // 4 independent fmac chains of depth 4
                float a0 = w[0] * g[0];
                float a1 = w[1] * g[1];
                float a2 = w[2] * g[2];
                float a3 = w[3] * g[3];
                a0 = fmaf(w[4],  g[4],  a0);
                a1 = fmaf(w[5],  g[5],  a1);
                a2 = fmaf(w[6],  g[6],  a2);
                a3 = fmaf(w[7],  g[7],  a3);
                a0 = fmaf(w[8],  g[8],  a0);
                a1 = fmaf(w[9],  g[9],  a1);
                a2 = fmaf(w[10], g[10], a2);
                a3 = fmaf(w[11], g[11], a3);
                a0 = fmaf(w[12], g[12], a0);
                a1 = fmaf(w[13], g[13], a1);
                a2 = fmaf(w[14], g[14], a2);
                a3 = fmaf(w[15], g[15], a3);
                const float p = (a0 + a1) + (a2 + a3); // my half's partial
                const float tot = swap32_add(p);       // own + partner half
                h = fmaxf(tot + xv, 0.0f);
                if (tt < 7)                            // off-chain x prefetch
                    xq[tt + 1] = *(const vf4*)(xb + (((tt + 1) * 4) ^ m));
            }
        }
        __builtin_amdgcn_s_setprio(0);

        // FC head: stage h once, then lane o (0..7) computes out[row][o].
        if (l < HID) hlds[l] = h;
        if (l < OUTD) {                 // same wave: LDS ops are in-order
            float s = bfc[l];
            #pragma unroll
            for (int j = 0; j < HID; ++j)
                s = fmaf(hlds[j], Wfc[l * HID + j], s);
            out[row * OUTD + l] = s;
        }
    } else {
        // ============================ PROJ ============================
        const int trow  = l & 31;          // timestep within chunk (A row)
        const int khalf = l >> 5;          // k-half selector
        const int irow  = l & 31;          // channel (B col / W_ih row)

        short8_t whi[8], wlo[8];
        #pragma unroll
        for (int kb = 0; kb < 8; ++kb) {
            const float* wp = Wih + irow * INCH + kb * 16 + khalf * 8;
            const float4 f0 = *(const float4*)(wp);
            const float4 f1 = *(const float4*)(wp + 4);
            split8(f0, f1, &whi[kb], &wlo[kb]);
        }
        const float biasv = bih[irow] + bhh[irow];
        const int m2 = 4 * (irow & 7);                  // store swizzle

        for (int c = 0; c < NCHUNK; ++c) {
            const float* sp = seq +
                ((size_t)row * TLEN + (size_t)c * TT + trow) * INCH + khalf * 8;
            short8_t ahi[8], alo[8];
            #pragma unroll
            for (int kb = 0; kb < 8; ++kb) {
                const float4 f0 = *(const float4*)(sp + kb * 16);
                const float4 f1 = *(const float4*)(sp + kb * 16 + 4);
                split8(f0, f1, &ahi[kb], &alo[kb]);
            }

            f32x16_t acc;
            #pragma unroll
            for (int r2 = 0; r2 < 16; ++r2) acc[r2] = biasv;
            #pragma unroll
            for (int kb = 0; kb < 8; ++kb) {
                acc = __builtin_amdgcn_mfma_f32_32x32x16_bf16(ahi[kb], whi[kb], acc, 0, 0, 0);
                acc = __builtin_amdgcn_mfma_f32_32x32x16_bf16(ahi[kb], wlo[kb], acc, 0, 0, 0);
                acc = __builtin_amdgcn_mfma_f32_32x32x16_bf16(alo[kb], whi[kb], acc, 0, 0, 0);
            }

            // D: lane holds 16 timesteps of channel irow -> transposed store,
            // 4x ds_write_b128 at t0 = 8g + 4*khalf (XOR-swizzled)
            float* xbT = xpb[c & 1] + irow * TT;
            #pragma unroll
            for (int g = 0; g < 4; ++g) {
                const int t0 = 8 * g + 4 * khalf;
                vf4 v;
                v.x = acc[4 * g + 0]; v.y = acc[4 * g + 1];
                v.z = acc[4 * g + 2]; v.w = acc[4 * g + 3];
                *(vf4*)(xbT + (t0 ^ m2)) = v;
            }
            __syncthreads();                            // publish chunk c
        }
    }
}

extern "C" void kernel_launch(void* const* d_in, const int* in_sizes, int n_in,
                              void* d_out, int out_size, void* d_ws, size_t ws_size,
                              hipStream_t stream) {
    const float* seq = (const float*)d_in[0];
    const float* Wih = (const float*)d_in[1];
    const float* Whh = (const float*)d_in[2];
    const float* bih = (const float*)d_in[3];
    const float* bhh = (const float*)d_in[4];
    const float* Wfc = (const float*)d_in[5];
    const float* bfc = (const float*)d_in[6];

    rnn_fused_kernel<<<dim3(BATCH), dim3(128), 0, stream>>>(
        seq, Wih, Whh, bih, bhh, Wfc, bfc, (float*)d_out);
}

// Round 10
// 51.832 us; speedup vs baseline: 1.5697x; 1.5697x over previous
//
#include <hip/hip_runtime.h>

#define HID   32
#define INCH  128
#define OUTD  8
#define BATCH 512
#define TLEN  512
#define TT    32
#define NCHUNK (TLEN / TT)

typedef __attribute__((ext_vector_type(2)))  float  f32x2;
typedef __attribute__((ext_vector_type(4)))  float  vf4;
typedef __attribute__((ext_vector_type(8)))  short  short8_t;
typedef __attribute__((ext_vector_type(16))) float  f32x16_t;
typedef __attribute__((ext_vector_type(2)))  int    i32x2;

// p_own + p[lane^32]  (HW-verified rounds 6/8)
__device__ __forceinline__ float swap32_add(float p)
{
#if __has_builtin(__builtin_amdgcn_permlane32_swap)
    i32x2 r = __builtin_amdgcn_permlane32_swap(
        __float_as_int(p), __float_as_int(p), false, false);
    return __int_as_float(r[0]) + __int_as_float(r[1]);
#else
    return p + __shfl_xor(p, 32, 64);
#endif
}

// Split fp32 -> bf16 hi (bit-truncate) + bf16 lo (truncated residual).
__device__ __forceinline__ void split8(const float4 f0, const float4 f1,
                                       short8_t* hi, short8_t* lo)
{
    float x[8] = {f0.x, f0.y, f0.z, f0.w, f1.x, f1.y, f1.z, f1.w};
    short8_t h, l;
    #pragma unroll
    for (int e = 0; e < 8; ++e) {
        const unsigned u  = __float_as_uint(x[e]);
        const unsigned hb = u & 0xFFFF0000u;
        h[e] = (short)(u >> 16);
        const float r = x[e] - __uint_as_float(hb);
        l[e] = (short)(__float_as_uint(r) >> 16);
    }
    *hi = h; *lo = l;
}

// ---------------------------------------------------------------------------
// One block per batch row; 2 waves. (Round-6 structure — best measured:
// 250 cyc/step — with two chain shavings.)
//   wave 0 (scan): h = relu(x_t + W_hh h), fp32.
//     - j-range split across half-waves: 4 ds_read_b128 on the chain
//     - cross-half combine via permlane32_swap (VALU)
//     - xv folded into half-0's partial via cndmask seed (computed during
//       the read-wait window; removes one dependent add from the tail)
//     - x prefetch issued BEFORE the h-write so it never delays the next
//       step's h-reads in the in-order LDS pipe
//   wave 1 (proj): split-bf16 MFMA 32x32x128 GEMM per chunk; D stored
//     transposed (XOR-swizzled) as 4x ds_write_b128 per lane.
// ---------------------------------------------------------------------------
__global__ __launch_bounds__(128, 1) void rnn_fused_kernel(
    const float* __restrict__ seq, const float* __restrict__ Wih,
    const float* __restrict__ Whh, const float* __restrict__ bih,
    const float* __restrict__ bhh, const float* __restrict__ Wfc,
    const float* __restrict__ bfc, float* __restrict__ out)
{
    __shared__ __align__(16) float xpb[2][TT * HID];   // transposed [ch][t], 8 KB
    __shared__ __align__(16) float hlds[64];           // 2 copies of h

    const int tid  = threadIdx.x;
    const int wid  = tid >> 6;
    const int l    = tid & 63;
    const int row  = blockIdx.x;

    if (wid == 0) {
        // ============================ SCAN ============================
        const int ch    = l & 31;
        const int half  = l >> 5;
        const int jbase = half * 16;
        const int m     = 4 * (ch & 7);                 // x swizzle (dwords)

        // W_hh[ch][jbase .. jbase+15] as 8 f32x2
        f32x2 w2[8];
        {
            const vf4* W4 = (const vf4*)(Whh + ch * HID + jbase);
            #pragma unroll
            for (int q = 0; q < 4; ++q) {
                const vf4 t = W4[q];
                w2[2 * q + 0] = t.xy;
                w2[2 * q + 1] = t.zw;
            }
        }

        hlds[l] = 0.0f;                                 // h0 = 0 (both copies)
        // low half reads h[0..15] (copy 0), high half h[16..31] (copy 1)
        const vf4* h4 = (const vf4*)&hlds[half * 48];

        __builtin_amdgcn_s_setprio(1);
        for (int c = 0; c < NCHUNK; ++c) {
            __syncthreads();                            // chunk c published
            const float* xb = xpb[c & 1] + ch * TT;     // my channel's column
            vf4 xq[8];
            xq[0] = *(const vf4*)(xb + m);              // x[0..3]

            #pragma unroll
            for (int tt = 0; tt < TT; ++tt) {
                const float xv = xq[tt >> 2][tt & 3];
                const float xs = half ? 0.0f : xv;      // cndmask, off-chain
                const vf4 h0 = h4[0];
                const vf4 h1 = h4[1];
                const vf4 h2 = h4[2];
                const vf4 h3 = h4[3];
                // x prefetch: issued after the h-reads, before the h-write,
                // so it completes inside the FMA window
                if (tt < 7)
                    xq[tt + 1] = *(const vf4*)(xb + (((tt + 1) * 4) ^ m));
                f32x2 seed; seed.x = xs; seed.y = 0.0f;
                f32x2 a0 = w2[0] * h0.xy + seed;
                f32x2 a1 = w2[1] * h0.zw;
                a0 = w2[2] * h1.xy + a0;
                a1 = w2[3] * h1.zw + a1;
                a0 = w2[4] * h2.xy + a0;
                a1 = w2[5] * h2.zw + a1;
                a0 = w2[6] * h3.xy + a0;
                a1 = w2[7] * h3.zw + a1;
                const f32x2 s2 = a0 + a1;
                const float p = s2.x + s2.y;            // half partial (+xv)
                const float tot = swap32_add(p);        // own + partner
                const float hn = fmaxf(tot, 0.0f);
                hlds[l] = hn;                           // publish for next step
            }
        }
        __builtin_amdgcn_s_setprio(0);

        // FC head: lane o (0..7) computes out[row][o] from hlds copy 0.
        if (l < OUTD) {
            float s = bfc[l];
            #pragma unroll
            for (int j = 0; j < HID; ++j)
                s = fmaf(hlds[j], Wfc[l * HID + j], s);
            out[row * OUTD + l] = s;
        }
    } else {
        // ============================ PROJ ============================
        const int trow  = l & 31;          // timestep within chunk (A row)
        const int khalf = l >> 5;          // k-half selector
        const int irow  = l & 31;          // channel (B col / W_ih row)

        short8_t whi[8], wlo[8];
        #pragma unroll
        for (int kb = 0; kb < 8; ++kb) {
            const float* wp = Wih + irow * INCH + kb * 16 + khalf * 8;
            const float4 f0 = *(const float4*)(wp);
            const float4 f1 = *(const float4*)(wp + 4);
            split8(f0, f1, &whi[kb], &wlo[kb]);
        }
        const float biasv = bih[irow] + bhh[irow];
        const int m2 = 4 * (irow & 7);                  // store swizzle

        for (int c = 0; c < NCHUNK; ++c) {
            const float* sp = seq +
                ((size_t)row * TLEN + (size_t)c * TT + trow) * INCH + khalf * 8;
            short8_t ahi[8], alo[8];
            #pragma unroll
            for (int kb = 0; kb < 8; ++kb) {
                const float4 f0 = *(const float4*)(sp + kb * 16);
                const float4 f1 = *(const float4*)(sp + kb * 16 + 4);
                split8(f0, f1, &ahi[kb], &alo[kb]);
            }

            f32x16_t acc;
            #pragma unroll
            for (int r2 = 0; r2 < 16; ++r2) acc[r2] = biasv;
            #pragma unroll
            for (int kb = 0; kb < 8; ++kb) {
                acc = __builtin_amdgcn_mfma_f32_32x32x16_bf16(ahi[kb], whi[kb], acc, 0, 0, 0);
                acc = __builtin_amdgcn_mfma_f32_32x32x16_bf16(ahi[kb], wlo[kb], acc, 0, 0, 0);
                acc = __builtin_amdgcn_mfma_f32_32x32x16_bf16(alo[kb], whi[kb], acc, 0, 0, 0);
            }

            // D: lane holds 16 timesteps of channel irow -> transposed store,
            // 4x ds_write_b128 at t0 = 8g + 4*khalf (XOR-swizzled)
            float* xbT = xpb[c & 1] + irow * TT;
            #pragma unroll
            for (int g = 0; g < 4; ++g) {
                const int t0 = 8 * g + 4 * khalf;
                vf4 v;
                v.x = acc[4 * g + 0]; v.y = acc[4 * g + 1];
                v.z = acc[4 * g + 2]; v.w = acc[4 * g + 3];
                *(vf4*)(xbT + (t0 ^ m2)) = v;
            }
            __syncthreads();                            // publish chunk c
        }
    }
}

extern "C" void kernel_launch(void* const* d_in, const int* in_sizes, int n_in,
                              void* d_out, int out_size, void* d_ws, size_t ws_size,
                              hipStream_t stream) {
    const float* seq = (const float*)d_in[0];
    const float* Wih = (const float*)d_in[1];
    const float* Whh = (const float*)d_in[2];
    const float* bih = (const float*)d_in[3];
    const float* bhh = (const float*)d_in[4];
    const float* Wfc = (const float*)d_in[5];
    const float* bfc = (const float*)d_in[6];

    rnn_fused_kernel<<<dim3(BATCH), dim3(128), 0, stream>>>(
        seq, Wih, Whh, bih, bhh, Wfc, bfc, (float*)d_out);
}